// Round 2
// baseline (773.317 us; speedup 1.0000x reference)
//
#include <hip/hip_runtime.h>
#include <cstdint>

// GCGRU cell, restructured:
//   Zg = [x;h] (1536x4000)  -> Z1 = Zg A^T, Z2 = Z1 A^T      (shared by r,u)
//   gates: r,u = sigmoid(W{f,u} . [Zg;Z1;Z2] + b)            (fp32 conv)
//   rh = r*h (1024x4000)    -> Rh1 = rh A^T, Rh2 = Rh1 A^T
//   cand: c = tanh(Wc . [x,rh, Ax,Arh, A2x,A2rh] + bc);  out = u h + (1-u) c
// Diffusion GEMMs in bf16 MFMA (fp32 accum); A x / A^2 x reused from Z1/Z2.
// All padded to K=N=4096; adj pad rows/cols are ZERO so pad K-cols self-mask.
//
// Round-2 change (theory-only; no bench signal yet): split-K GEMM.
//   Grid was 256-384 blocks = 1 block/CU = 1 wave/SIMD -> ~320 TF regime
//   (m102). One launch with gridDim.z = split chunks writing fp32 partials,
//   then a combine kernel. split in {4,2,1} chosen from ws_size at launch
//   (same choice every call -> graph-safe).

#define NREAL 4000
#define NPAD  4096

typedef unsigned short u16;
typedef __attribute__((ext_vector_type(8))) short short8;
typedef __attribute__((ext_vector_type(4))) float f32x4;
typedef __attribute__((ext_vector_type(4))) unsigned short u16x4;

__device__ __forceinline__ u16 f2bf(float f) {
  unsigned u = __builtin_bit_cast(unsigned, f);
  return (u16)((u + 0x7FFFu + ((u >> 16) & 1u)) >> 16);
}
__device__ __forceinline__ float bf2f(u16 b) {
  unsigned u = ((unsigned)b) << 16;
  return __builtin_bit_cast(float, u);
}

// ---- adj f32 [4000][4000] -> bf16 [4096][4096], zero-padded ----
__global__ __launch_bounds__(256) void k_pack_adj(const float* __restrict__ adj,
                                                  u16* __restrict__ out) {
  const int idx = blockIdx.x * 256 + threadIdx.x;   // 4096*1024 total
  const int m = idx >> 10;
  const int n0 = (idx & 1023) << 2;
  u16x4 o;
  if (m < NREAL && n0 < NREAL) {   // 4000%4==0 so a float4 never straddles the edge
    const float4 v = *reinterpret_cast<const float4*>(&adj[(long)m * NREAL + n0]);
    o.x = f2bf(v.x); o.y = f2bf(v.y); o.z = f2bf(v.z); o.w = f2bf(v.w);
  } else {
    o.x = 0; o.y = 0; o.z = 0; o.w = 0;
  }
  *reinterpret_cast<u16x4*>(&out[(long)m * NPAD + n0]) = o;
}

// ---- Zg bf16 [1536][4096] = rows (b*96+c): c<32 -> x, else h ----
__global__ __launch_bounds__(256) void k_pack_zg(const float* __restrict__ x,
                                                 const float* __restrict__ h,
                                                 u16* __restrict__ zg) {
  const int idx = blockIdx.x * 256 + threadIdx.x;   // 1536*1024 total
  const int row = idx >> 10;
  const int n0 = (idx & 1023) << 2;
  const int b = row / 96, c = row % 96;
  const float* src = (c < 32) ? &x[((long)b * 32 + c) * NREAL]
                              : &h[((long)b * 64 + (c - 32)) * NREAL];
  u16x4 o;
  if (n0 < NREAL) {
    const float4 v = *reinterpret_cast<const float4*>(&src[n0]);
    o.x = f2bf(v.x); o.y = f2bf(v.y); o.z = f2bf(v.z); o.w = f2bf(v.w);
  } else {
    o.x = 0; o.y = 0; o.z = 0; o.w = 0;
  }
  *reinterpret_cast<u16x4*>(&zg[(long)row * NPAD + n0]) = o;
}

// ---- NT bf16 GEMM: C[i][m] = sum_n A[i][n] * B[m][n], all [.][4096] bf16 ----
// m97 structure: 128x128 tile, BK=32, 4 waves, global_load_lds(16B), 16x16x32.
// F32OUT: blockIdx.z selects K-chunk, writes fp32 partial at z*chunkElems.
template<bool F32OUT>
__global__ __launch_bounds__(256) void k_gemm_bt(const u16* __restrict__ A,
                                                 const u16* __restrict__ B,
                                                 void* __restrict__ Cout,
                                                 int ktPerChunk, long chunkElems) {
  __shared__ __align__(16) u16 As[128 * 32];
  __shared__ __align__(16) u16 Bs[128 * 32];
  const int tid = threadIdx.x;
  const int wave = tid >> 6;
  const int lane = tid & 63;
  const int bn = blockIdx.x;        // N tile
  const int bm = blockIdx.y;        // M tile
  const int ktBegin = blockIdx.z * ktPerChunk;
  const int ktEnd = ktBegin + ktPerChunk;

  // staging: each lane delivers one 16B slot; wave covers 16 rows per issue
  const int srow = (wave << 4) + (lane >> 2);
  const int sslot = (lane & 3) << 3;                 // element offset of slot
  const long aRow  = (long)(bm * 128 + srow) * NPAD;
  const long aRow2 = aRow + 64L * NPAD;
  const long bRow  = (long)(bn * 128 + srow) * NPAD;
  const long bRow2 = bRow + 64L * NPAD;
  const int wbase = __builtin_amdgcn_readfirstlane(wave << 9);  // wave LDS base

  const int wr = (wave >> 1) << 6;   // wave row origin in tile
  const int wc = (wave & 1) << 6;    // wave col origin
  const int fr = lane & 15;
  const int ks = (lane >> 4) << 3;   // k element offset of this lane's chunk

  f32x4 acc[4][4] = {};

  for (int kt = ktBegin; kt < ktEnd; ++kt) {
    const long kofs = (long)kt * 32 + sslot;
    __syncthreads();   // prior ds_reads done before overwrite
    __builtin_amdgcn_global_load_lds(
        (const __attribute__((address_space(1))) void*)(A + aRow + kofs),
        (__attribute__((address_space(3))) void*)(&As[wbase]), 16, 0, 0);
    __builtin_amdgcn_global_load_lds(
        (const __attribute__((address_space(1))) void*)(A + aRow2 + kofs),
        (__attribute__((address_space(3))) void*)(&As[wbase + 2048]), 16, 0, 0);
    __builtin_amdgcn_global_load_lds(
        (const __attribute__((address_space(1))) void*)(B + bRow + kofs),
        (__attribute__((address_space(3))) void*)(&Bs[wbase]), 16, 0, 0);
    __builtin_amdgcn_global_load_lds(
        (const __attribute__((address_space(1))) void*)(B + bRow2 + kofs),
        (__attribute__((address_space(3))) void*)(&Bs[wbase + 2048]), 16, 0, 0);
    __syncthreads();   // vmcnt(0)+lgkmcnt(0) drained by compiler before barrier

    short8 av[4], bv[4];
#pragma unroll
    for (int i = 0; i < 4; ++i) {
      av[i] = *reinterpret_cast<const short8*>(&As[(wr + (i << 4) + fr) * 32 + ks]);
      bv[i] = *reinterpret_cast<const short8*>(&Bs[(wc + (i << 4) + fr) * 32 + ks]);
    }
#pragma unroll
    for (int i = 0; i < 4; ++i)
#pragma unroll
      for (int j = 0; j < 4; ++j)
        acc[i][j] = __builtin_amdgcn_mfma_f32_16x16x32_bf16(av[i], bv[j], acc[i][j], 0, 0, 0);
  }

  // C/D layout (m89-verified): col = lane&15, row = (lane>>4)*4 + q
  const int rb = bm * 128 + wr + ((lane >> 4) << 2);
  const int cb = bn * 128 + wc + fr;
  if (F32OUT) {
    float* C = (float*)Cout + (long)blockIdx.z * chunkElems;
#pragma unroll
    for (int i = 0; i < 4; ++i)
#pragma unroll
      for (int j = 0; j < 4; ++j)
#pragma unroll
        for (int q = 0; q < 4; ++q)
          C[(long)(rb + (i << 4) + q) * NPAD + cb + (j << 4)] = acc[i][j][q];
  } else {
    u16* C = (u16*)Cout;
#pragma unroll
    for (int i = 0; i < 4; ++i)
#pragma unroll
      for (int j = 0; j < 4; ++j)
#pragma unroll
        for (int q = 0; q < 4; ++q)
          C[(long)(rb + (i << 4) + q) * NPAD + cb + (j << 4)] = f2bf(acc[i][j][q]);
  }
}

// ---- sum NC fp32 partial chunks -> bf16 ----
template<int NC>
__global__ __launch_bounds__(256) void k_combine(const float* __restrict__ P,
                                                 long chunkElems,
                                                 u16* __restrict__ out) {
  const long i4 = ((long)blockIdx.x * 256 + threadIdx.x) * 4;
  f32x4 s = *reinterpret_cast<const f32x4*>(&P[i4]);
#pragma unroll
  for (int c = 1; c < NC; ++c) {
    const f32x4 v = *reinterpret_cast<const f32x4*>(&P[(long)c * chunkElems + i4]);
    s.x += v.x; s.y += v.y; s.z += v.z; s.w += v.w;
  }
  u16x4 o;
  o.x = f2bf(s.x); o.y = f2bf(s.y); o.z = f2bf(s.z); o.w = f2bf(s.w);
  *reinterpret_cast<u16x4*>(&out[i4]) = o;
}

// ---- gates: r,u = sigmoid(W.[z;z1;z2]+b); emit rh(bf16 [+f32]), u(f32) ----
// one thread = one n position, 32 of 64 outputs (blockIdx.z halves)
__global__ __launch_bounds__(256) void k_gates(
    const float* __restrict__ x, const float* __restrict__ h,
    const float* __restrict__ Wf, const float* __restrict__ bfv,
    const float* __restrict__ Wu, const float* __restrict__ buv,
    const u16* __restrict__ Z1, const u16* __restrict__ Z2,
    u16* __restrict__ rh_bf, float* __restrict__ rh_f, float* __restrict__ u_f) {
  const int n = blockIdx.x * 256 + threadIdx.x;
  const int b = blockIdx.y;
  const int oh = blockIdx.z << 5;
  if (n >= NREAL) return;
  float af[32] = {}, au[32] = {};
  for (int c = 0; c < 96; ++c) {          // order-0: z = [x;h], fp32 exact
    const float f = (c < 32) ? x[((long)b * 32 + c) * NREAL + n]
                             : h[((long)b * 64 + (c - 32)) * NREAL + n];
#pragma unroll
    for (int o = 0; o < 32; ++o) {
      af[o] = fmaf(Wf[(oh + o) * 288 + c], f, af[o]);
      au[o] = fmaf(Wu[(oh + o) * 288 + c], f, au[o]);
    }
  }
  for (int c = 0; c < 96; ++c) {          // order-1
    const float f = bf2f(Z1[((long)b * 96 + c) * NPAD + n]);
#pragma unroll
    for (int o = 0; o < 32; ++o) {
      af[o] = fmaf(Wf[(oh + o) * 288 + 96 + c], f, af[o]);
      au[o] = fmaf(Wu[(oh + o) * 288 + 96 + c], f, au[o]);
    }
  }
  for (int c = 0; c < 96; ++c) {          // order-2
    const float f = bf2f(Z2[((long)b * 96 + c) * NPAD + n]);
#pragma unroll
    for (int o = 0; o < 32; ++o) {
      af[o] = fmaf(Wf[(oh + o) * 288 + 192 + c], f, af[o]);
      au[o] = fmaf(Wu[(oh + o) * 288 + 192 + c], f, au[o]);
    }
  }
#pragma unroll
  for (int o = 0; o < 32; ++o) {
    const int og = oh + o;
    const float r = 1.f / (1.f + __expf(-(af[o] + bfv[og])));
    const float u = 1.f / (1.f + __expf(-(au[o] + buv[og])));
    const long off = ((long)b * 64 + og) * NREAL + n;
    const float rh = r * h[off];
    if (rh_f) rh_f[off] = rh;
    u_f[off] = u;
    rh_bf[((long)b * 64 + og) * NPAD + n] = f2bf(rh);
  }
}

// ---- candidate + output: c = tanh(Wc.feats+bc); out = u h + (1-u) c ----
// RHF32: order-0 rh read from fp32 buffer (exact); else from bf16 Rhb.
template<bool RHF32>
__global__ __launch_bounds__(256) void k_cand(
    const float* __restrict__ x, const float* __restrict__ h,
    const float* __restrict__ Wc, const float* __restrict__ bcv,
    const u16* __restrict__ Z1, const u16* __restrict__ Z2,
    const u16* __restrict__ Rhb, const u16* __restrict__ Rh1,
    const u16* __restrict__ Rh2,
    const float* __restrict__ rh_f, const float* __restrict__ u_f,
    float* __restrict__ out) {
  const int n = blockIdx.x * 256 + threadIdx.x;
  const int b = blockIdx.y;
  const int oh = blockIdx.z << 5;
  if (n >= NREAL) return;
  float ac[32] = {};
  for (int c = 0; c < 32; ++c) {          // x (order 0)
    const float f = x[((long)b * 32 + c) * NREAL + n];
#pragma unroll
    for (int o = 0; o < 32; ++o) ac[o] = fmaf(Wc[(oh + o) * 288 + c], f, ac[o]);
  }
  for (int c = 0; c < 64; ++c) {          // rh (order 0)
    const float f = RHF32 ? rh_f[((long)b * 64 + c) * NREAL + n]
                          : bf2f(Rhb[((long)b * 64 + c) * NPAD + n]);
#pragma unroll
    for (int o = 0; o < 32; ++o) ac[o] = fmaf(Wc[(oh + o) * 288 + 32 + c], f, ac[o]);
  }
  for (int c = 0; c < 32; ++c) {          // A x  (reused from Z1: x-part rows)
    const float f = bf2f(Z1[((long)b * 96 + c) * NPAD + n]);
#pragma unroll
    for (int o = 0; o < 32; ++o) ac[o] = fmaf(Wc[(oh + o) * 288 + 96 + c], f, ac[o]);
  }
  for (int c = 0; c < 64; ++c) {          // A rh
    const float f = bf2f(Rh1[((long)b * 64 + c) * NPAD + n]);
#pragma unroll
    for (int o = 0; o < 32; ++o) ac[o] = fmaf(Wc[(oh + o) * 288 + 128 + c], f, ac[o]);
  }
  for (int c = 0; c < 32; ++c) {          // A^2 x (reused from Z2)
    const float f = bf2f(Z2[((long)b * 96 + c) * NPAD + n]);
#pragma unroll
    for (int o = 0; o < 32; ++o) ac[o] = fmaf(Wc[(oh + o) * 288 + 192 + c], f, ac[o]);
  }
  for (int c = 0; c < 64; ++c) {          // A^2 rh
    const float f = bf2f(Rh2[((long)b * 64 + c) * NPAD + n]);
#pragma unroll
    for (int o = 0; o < 32; ++o) ac[o] = fmaf(Wc[(oh + o) * 288 + 224 + c], f, ac[o]);
  }
#pragma unroll
  for (int o = 0; o < 32; ++o) {
    const int og = oh + o;
    const long off = ((long)b * 64 + og) * NREAL + n;
    float v = ac[o] + bcv[og];
    v = fminf(fmaxf(v, -15.f), 15.f);
    const float e2 = __expf(2.f * v);
    const float cv = (e2 - 1.f) / (e2 + 1.f);
    const float u = u_f[off];
    out[off] = u * h[off] + (1.f - u) * cv;
  }
}

extern "C" void kernel_launch(void* const* d_in, const int* in_sizes, int n_in,
                              void* d_out, int out_size, void* d_ws, size_t ws_size,
                              hipStream_t stream) {
  const float* x   = (const float*)d_in[0];
  const float* h   = (const float*)d_in[1];
  const float* adj = (const float*)d_in[2];
  const float* Wf  = (const float*)d_in[3];
  const float* bf_ = (const float*)d_in[4];
  const float* Wu  = (const float*)d_in[5];
  const float* bu_ = (const float*)d_in[6];
  const float* Wc  = (const float*)d_in[7];
  const float* bc_ = (const float*)d_in[8];
  float* out = (float*)d_out;

  char* p = (char*)d_ws;
  auto alloc = [&](size_t bytes) { char* r = p; p += bytes; return r; };
  u16* adjb = (u16*)alloc((size_t)NPAD * NPAD * 2);       // 33.55 MB
  u16* Zg   = (u16*)alloc((size_t)1536 * NPAD * 2);       // 12.58 MB (Rhb aliases: Zg dead after GEMM1)
  u16* Rhb  = Zg;
  u16* Z1   = (u16*)alloc((size_t)1536 * NPAD * 2);
  u16* Z2   = (u16*)alloc((size_t)1536 * NPAD * 2);
  u16* Rh1  = (u16*)alloc((size_t)1024 * NPAD * 2);       // 8.39 MB
  u16* Rh2  = (u16*)alloc((size_t)1024 * NPAD * 2);
  float* uf = (float*)alloc((size_t)16 * 64 * NREAL * 4); // 16.38 MB
  const size_t RHFB = (size_t)16 * 64 * NREAL * 4;
  const size_t PC = (size_t)1536 * NPAD * 4;              // 25.17 MB / chunk
  size_t used = (size_t)(p - (char*)d_ws);
  float* rhf = nullptr;
  if (ws_size >= used + RHFB) rhf = (float*)alloc(RHFB);
  used = (size_t)(p - (char*)d_ws);
  int split = 1;
  float* P = nullptr;
  if (ws_size >= used + 4 * PC) { split = 4; P = (float*)alloc(4 * PC); }
  else if (ws_size >= used + 2 * PC) { split = 2; P = (float*)alloc(2 * PC); }

  auto gemm = [&](const u16* A, const u16* B, u16* Cb, int M) {
    const long ce = (long)M * NPAD;
    if (split == 4) {
      k_gemm_bt<true><<<dim3(32, M / 128, 4), 256, 0, stream>>>(A, B, P, 32, ce);
      k_combine<4><<<dim3(M * 4), 256, 0, stream>>>(P, ce, Cb);
    } else if (split == 2) {
      k_gemm_bt<true><<<dim3(32, M / 128, 2), 256, 0, stream>>>(A, B, P, 64, ce);
      k_combine<2><<<dim3(M * 4), 256, 0, stream>>>(P, ce, Cb);
    } else {
      k_gemm_bt<false><<<dim3(32, M / 128, 1), 256, 0, stream>>>(A, B, Cb, 128, ce);
    }
  };

  k_pack_adj<<<dim3(NPAD * (NPAD / 4) / 256), 256, 0, stream>>>(adj, adjb);
  k_pack_zg <<<dim3(1536 * (NPAD / 4) / 256), 256, 0, stream>>>(x, h, Zg);
  gemm(Zg, adjb, Z1, 1536);                                   // Z1 = Zg A^T
  gemm(Z1, adjb, Z2, 1536);                                   // Z2 = Z1 A^T
  k_gates<<<dim3(16, 16, 2), 256, 0, stream>>>(x, h, Wf, bf_, Wu, bu_, Z1, Z2,
                                               Rhb, rhf, uf);
  gemm(Rhb, adjb, Rh1, 1024);                                 // Rh1 = rh A^T
  gemm(Rh1, adjb, Rh2, 1024);                                 // Rh2 = Rh1 A^T
  if (rhf)
    k_cand<true><<<dim3(16, 16, 2), 256, 0, stream>>>(x, h, Wc, bc_, Z1, Z2, Rhb,
                                                      Rh1, Rh2, rhf, uf, out);
  else
    k_cand<false><<<dim3(16, 16, 2), 256, 0, stream>>>(x, h, Wc, bc_, Z1, Z2, Rhb,
                                                       Rh1, Rh2, rhf, uf, out);
}

// Round 3
// 546.589 us; speedup vs baseline: 1.4148x; 1.4148x over previous
//
#include <hip/hip_runtime.h>
#include <cstdint>

// GCGRU cell, restructured:
//   Zg = [x;h] (1536x4000)  -> Z1 = Zg A^T, Z2 = Z1 A^T      (shared by r,u)
//   gates: r,u = sigmoid(W{f,u} . [Zg;Z1;Z2] + b)            (fp32 conv)
//   rh = r*h (1024x4000)    -> Rh1 = rh A^T, Rh2 = Rh1 A^T
//   cand: c = tanh(Wc . [x,rh, Ax,Arh, A2x,A2rh] + bc);  out = u h + (1-u) c
// Diffusion GEMMs in bf16 MFMA (fp32 accum, split-K); gate/cand convs fp32.
//
// Round-3 change: k_gates/k_cand were scratch-spilled (VGPR=40 w/ 64 accs,
// 239 us, VALUBusy 22%). Rewritten: wave owns 16 outputs, W pre-transposed
// to [c][o] so per-c weights are 16 contiguous wave-uniform floats (s_load),
// lanes own n. Statically indexed acc arrays stay in VGPRs.

#define NREAL 4000
#define NPAD  4096

typedef unsigned short u16;
typedef __attribute__((ext_vector_type(8))) short short8;
typedef __attribute__((ext_vector_type(4))) float f32x4;
typedef __attribute__((ext_vector_type(4))) unsigned short u16x4;

__device__ __forceinline__ u16 f2bf(float f) {
  unsigned u = __builtin_bit_cast(unsigned, f);
  return (u16)((u + 0x7FFFu + ((u >> 16) & 1u)) >> 16);
}
__device__ __forceinline__ float bf2f(u16 b) {
  unsigned u = ((unsigned)b) << 16;
  return __builtin_bit_cast(float, u);
}

// ---- adj f32 [4000][4000] -> bf16 [4096][4096], zero-padded ----
__global__ __launch_bounds__(256) void k_pack_adj(const float* __restrict__ adj,
                                                  u16* __restrict__ out) {
  const int idx = blockIdx.x * 256 + threadIdx.x;   // 4096*1024 total
  const int m = idx >> 10;
  const int n0 = (idx & 1023) << 2;
  u16x4 o;
  if (m < NREAL && n0 < NREAL) {   // 4000%4==0 so a float4 never straddles the edge
    const float4 v = *reinterpret_cast<const float4*>(&adj[(long)m * NREAL + n0]);
    o.x = f2bf(v.x); o.y = f2bf(v.y); o.z = f2bf(v.z); o.w = f2bf(v.w);
  } else {
    o.x = 0; o.y = 0; o.z = 0; o.w = 0;
  }
  *reinterpret_cast<u16x4*>(&out[(long)m * NPAD + n0]) = o;
}

// ---- Zg bf16 [1536][4096] = rows (b*96+c): c<32 -> x, else h ----
__global__ __launch_bounds__(256) void k_pack_zg(const float* __restrict__ x,
                                                 const float* __restrict__ h,
                                                 u16* __restrict__ zg) {
  const int idx = blockIdx.x * 256 + threadIdx.x;   // 1536*1024 total
  const int row = idx >> 10;
  const int n0 = (idx & 1023) << 2;
  const int b = row / 96, c = row % 96;
  const float* src = (c < 32) ? &x[((long)b * 32 + c) * NREAL]
                              : &h[((long)b * 64 + (c - 32)) * NREAL];
  u16x4 o;
  if (n0 < NREAL) {
    const float4 v = *reinterpret_cast<const float4*>(&src[n0]);
    o.x = f2bf(v.x); o.y = f2bf(v.y); o.z = f2bf(v.z); o.w = f2bf(v.w);
  } else {
    o.x = 0; o.y = 0; o.z = 0; o.w = 0;
  }
  *reinterpret_cast<u16x4*>(&zg[(long)row * NPAD + n0]) = o;
}

// ---- W transpose pack: Wgt[c][128] = [Wf;Wu]^T, Wct[c][64] = Wc^T ----
__global__ __launch_bounds__(256) void k_pack_w(const float* __restrict__ Wf,
                                                const float* __restrict__ Wu,
                                                const float* __restrict__ Wc,
                                                float* __restrict__ Wgt,
                                                float* __restrict__ Wct) {
  const int idx = blockIdx.x * 256 + threadIdx.x;   // 144 blocks
  if (idx < 288 * 128) {
    const int c = idx >> 7, o = idx & 127;
    Wgt[idx] = (o < 64) ? Wf[o * 288 + c] : Wu[(o - 64) * 288 + c];
  }
  if (idx < 288 * 64) {
    const int c = idx >> 6, o = idx & 63;
    Wct[idx] = Wc[o * 288 + c];
  }
}

// ---- NT bf16 GEMM: C[i][m] = sum_n A[i][n] * B[m][n], all [.][4096] bf16 ----
// m97 structure: 128x128 tile, BK=32, 4 waves, global_load_lds(16B), 16x16x32.
// F32OUT: blockIdx.z selects K-chunk, writes fp32 partial at z*chunkElems.
template<bool F32OUT>
__global__ __launch_bounds__(256) void k_gemm_bt(const u16* __restrict__ A,
                                                 const u16* __restrict__ B,
                                                 void* __restrict__ Cout,
                                                 int ktPerChunk, long chunkElems) {
  __shared__ __align__(16) u16 As[128 * 32];
  __shared__ __align__(16) u16 Bs[128 * 32];
  const int tid = threadIdx.x;
  const int wave = tid >> 6;
  const int lane = tid & 63;
  const int bn = blockIdx.x;        // N tile
  const int bm = blockIdx.y;        // M tile
  const int ktBegin = blockIdx.z * ktPerChunk;
  const int ktEnd = ktBegin + ktPerChunk;

  const int srow = (wave << 4) + (lane >> 2);
  const int sslot = (lane & 3) << 3;                 // element offset of slot
  const long aRow  = (long)(bm * 128 + srow) * NPAD;
  const long aRow2 = aRow + 64L * NPAD;
  const long bRow  = (long)(bn * 128 + srow) * NPAD;
  const long bRow2 = bRow + 64L * NPAD;
  const int wbase = __builtin_amdgcn_readfirstlane(wave << 9);  // wave LDS base

  const int wr = (wave >> 1) << 6;   // wave row origin in tile
  const int wc = (wave & 1) << 6;    // wave col origin
  const int fr = lane & 15;
  const int ks = (lane >> 4) << 3;   // k element offset of this lane's chunk

  f32x4 acc[4][4] = {};

  for (int kt = ktBegin; kt < ktEnd; ++kt) {
    const long kofs = (long)kt * 32 + sslot;
    __syncthreads();   // prior ds_reads done before overwrite
    __builtin_amdgcn_global_load_lds(
        (const __attribute__((address_space(1))) void*)(A + aRow + kofs),
        (__attribute__((address_space(3))) void*)(&As[wbase]), 16, 0, 0);
    __builtin_amdgcn_global_load_lds(
        (const __attribute__((address_space(1))) void*)(A + aRow2 + kofs),
        (__attribute__((address_space(3))) void*)(&As[wbase + 2048]), 16, 0, 0);
    __builtin_amdgcn_global_load_lds(
        (const __attribute__((address_space(1))) void*)(B + bRow + kofs),
        (__attribute__((address_space(3))) void*)(&Bs[wbase]), 16, 0, 0);
    __builtin_amdgcn_global_load_lds(
        (const __attribute__((address_space(1))) void*)(B + bRow2 + kofs),
        (__attribute__((address_space(3))) void*)(&Bs[wbase + 2048]), 16, 0, 0);
    __syncthreads();   // vmcnt(0)+lgkmcnt(0) drained by compiler before barrier

    short8 av[4], bv[4];
#pragma unroll
    for (int i = 0; i < 4; ++i) {
      av[i] = *reinterpret_cast<const short8*>(&As[(wr + (i << 4) + fr) * 32 + ks]);
      bv[i] = *reinterpret_cast<const short8*>(&Bs[(wc + (i << 4) + fr) * 32 + ks]);
    }
#pragma unroll
    for (int i = 0; i < 4; ++i)
#pragma unroll
      for (int j = 0; j < 4; ++j)
        acc[i][j] = __builtin_amdgcn_mfma_f32_16x16x32_bf16(av[i], bv[j], acc[i][j], 0, 0, 0);
  }

  // C/D layout (m89-verified): col = lane&15, row = (lane>>4)*4 + q
  const int rb = bm * 128 + wr + ((lane >> 4) << 2);
  const int cb = bn * 128 + wc + fr;
  if (F32OUT) {
    float* C = (float*)Cout + (long)blockIdx.z * chunkElems;
#pragma unroll
    for (int i = 0; i < 4; ++i)
#pragma unroll
      for (int j = 0; j < 4; ++j)
#pragma unroll
        for (int q = 0; q < 4; ++q)
          C[(long)(rb + (i << 4) + q) * NPAD + cb + (j << 4)] = acc[i][j][q];
  } else {
    u16* C = (u16*)Cout;
#pragma unroll
    for (int i = 0; i < 4; ++i)
#pragma unroll
      for (int j = 0; j < 4; ++j)
#pragma unroll
        for (int q = 0; q < 4; ++q)
          C[(long)(rb + (i << 4) + q) * NPAD + cb + (j << 4)] = f2bf(acc[i][j][q]);
  }
}

// ---- sum NC fp32 partial chunks -> bf16 ----
template<int NC>
__global__ __launch_bounds__(256) void k_combine(const float* __restrict__ P,
                                                 long chunkElems,
                                                 u16* __restrict__ out) {
  const long i4 = ((long)blockIdx.x * 256 + threadIdx.x) * 4;
  f32x4 s = *reinterpret_cast<const f32x4*>(&P[i4]);
#pragma unroll
  for (int c = 1; c < NC; ++c) {
    const f32x4 v = *reinterpret_cast<const f32x4*>(&P[(long)c * chunkElems + i4]);
    s.x += v.x; s.y += v.y; s.z += v.z; s.w += v.w;
  }
  u16x4 o;
  o.x = f2bf(s.x); o.y = f2bf(s.y); o.z = f2bf(s.z); o.w = f2bf(s.w);
  *reinterpret_cast<u16x4*>(&out[i4]) = o;
}

// ---- gates: r,u = sigmoid(Wgt^T.[z;z1;z2]+b); emit rh(bf16 [+f32]), u(f32) ----
// 8 waves: wave wq owns 16 combined outputs (0-63 r, 64-127 u); lane owns 2 n.
// Wgt[c][128]: per-c weights wave-uniform & contiguous -> scalar loads.
__global__ __launch_bounds__(512) void k_gates(
    const float* __restrict__ x, const float* __restrict__ h,
    const float* __restrict__ Wgt,
    const float* __restrict__ bfv, const float* __restrict__ buv,
    const u16* __restrict__ Z1, const u16* __restrict__ Z2,
    u16* __restrict__ rh_bf, float* __restrict__ rh_f, float* __restrict__ u_f) {
  const int lane = threadIdx.x & 63;
  const int wq = __builtin_amdgcn_readfirstlane(threadIdx.x >> 6);  // 0..7
  const int b = blockIdx.y;
  const int n0 = blockIdx.x * 128 + (lane << 1);
  if (n0 >= NREAL) return;
  const int ob = wq << 4;                       // 16 outputs, combined index
  const float* xb = x + (long)b * 32 * NREAL + n0;
  const float* hb = h + (long)b * 64 * NREAL + n0;
  const u16* z1b = Z1 + (long)b * 96 * NPAD + n0;
  const u16* z2b = Z2 + (long)b * 96 * NPAD + n0;

  float a0[16] = {}, a1[16] = {};
#pragma unroll 4
  for (int c = 0; c < 32; ++c) {                // order-0: x
    const float2 f = *reinterpret_cast<const float2*>(&xb[(long)c * NREAL]);
#pragma unroll
    for (int oi = 0; oi < 16; ++oi) {
      const float w = Wgt[c * 128 + ob + oi];
      a0[oi] = fmaf(w, f.x, a0[oi]); a1[oi] = fmaf(w, f.y, a1[oi]);
    }
  }
#pragma unroll 4
  for (int c = 0; c < 64; ++c) {                // order-0: h
    const float2 f = *reinterpret_cast<const float2*>(&hb[(long)c * NREAL]);
#pragma unroll
    for (int oi = 0; oi < 16; ++oi) {
      const float w = Wgt[(32 + c) * 128 + ob + oi];
      a0[oi] = fmaf(w, f.x, a0[oi]); a1[oi] = fmaf(w, f.y, a1[oi]);
    }
  }
#pragma unroll 4
  for (int c = 0; c < 96; ++c) {                // order-1
    const unsigned pv = *reinterpret_cast<const unsigned*>(&z1b[(long)c * NPAD]);
    const float f0 = bf2f((u16)(pv & 0xffff)), f1 = bf2f((u16)(pv >> 16));
#pragma unroll
    for (int oi = 0; oi < 16; ++oi) {
      const float w = Wgt[(96 + c) * 128 + ob + oi];
      a0[oi] = fmaf(w, f0, a0[oi]); a1[oi] = fmaf(w, f1, a1[oi]);
    }
  }
#pragma unroll 4
  for (int c = 0; c < 96; ++c) {                // order-2
    const unsigned pv = *reinterpret_cast<const unsigned*>(&z2b[(long)c * NPAD]);
    const float f0 = bf2f((u16)(pv & 0xffff)), f1 = bf2f((u16)(pv >> 16));
#pragma unroll
    for (int oi = 0; oi < 16; ++oi) {
      const float w = Wgt[(192 + c) * 128 + ob + oi];
      a0[oi] = fmaf(w, f0, a0[oi]); a1[oi] = fmaf(w, f1, a1[oi]);
    }
  }

  if (wq < 4) {                                 // r outputs -> rh
#pragma unroll
    for (int oi = 0; oi < 16; ++oi) {
      const int og = ob + oi;
      const float bb = bfv[og];
      const float r0 = 1.f / (1.f + __expf(-(a0[oi] + bb)));
      const float r1 = 1.f / (1.f + __expf(-(a1[oi] + bb)));
      const float2 hv = *reinterpret_cast<const float2*>(&hb[(long)og * NREAL]);
      const float rh0 = r0 * hv.x, rh1 = r1 * hv.y;
      if (rh_f)
        *reinterpret_cast<float2*>(&rh_f[((long)b * 64 + og) * NREAL + n0]) =
            make_float2(rh0, rh1);
      const unsigned pk = (unsigned)f2bf(rh0) | ((unsigned)f2bf(rh1) << 16);
      *reinterpret_cast<unsigned*>(&rh_bf[((long)b * 64 + og) * NPAD + n0]) = pk;
    }
  } else {                                      // u outputs
#pragma unroll
    for (int oi = 0; oi < 16; ++oi) {
      const int og = (ob - 64) + oi;
      const float bb = buv[og];
      const float u0 = 1.f / (1.f + __expf(-(a0[oi] + bb)));
      const float u1 = 1.f / (1.f + __expf(-(a1[oi] + bb)));
      *reinterpret_cast<float2*>(&u_f[((long)b * 64 + og) * NREAL + n0]) =
          make_float2(u0, u1);
    }
  }
}

// ---- candidate + output: c = tanh(Wct^T.feats+bc); out = u h + (1-u) c ----
// 8 waves: o-group = wq&3 (16 outs), n-sub = wq>>2; lane owns 1 n.
template<bool RHF32>
__global__ __launch_bounds__(512) void k_cand(
    const float* __restrict__ x, const float* __restrict__ h,
    const float* __restrict__ Wct, const float* __restrict__ bcv,
    const u16* __restrict__ Z1, const u16* __restrict__ Z2,
    const u16* __restrict__ Rhb, const u16* __restrict__ Rh1,
    const u16* __restrict__ Rh2,
    const float* __restrict__ rh_f, const float* __restrict__ u_f,
    float* __restrict__ out) {
  const int lane = threadIdx.x & 63;
  const int wq = __builtin_amdgcn_readfirstlane(threadIdx.x >> 6);  // 0..7
  const int ob = (wq & 3) << 4;                 // 16 outputs
  const int n = blockIdx.x * 128 + ((wq >> 2) << 6) + lane;
  const int b = blockIdx.y;
  if (n >= NREAL) return;
  const float* xb = x + (long)b * 32 * NREAL + n;
  const float* hb = h + (long)b * 64 * NREAL + n;
  const u16* z1b = Z1 + (long)b * 96 * NPAD + n;
  const u16* z2b = Z2 + (long)b * 96 * NPAD + n;
  const u16* r1b = Rh1 + (long)b * 64 * NPAD + n;
  const u16* r2b = Rh2 + (long)b * 64 * NPAD + n;
  const float* rfb = rh_f + (long)b * 64 * NREAL + n;
  const u16* rbb = Rhb + (long)b * 64 * NPAD + n;

  float acc[16] = {};
#pragma unroll 4
  for (int c = 0; c < 32; ++c) {                // x
    const float f = xb[(long)c * NREAL];
#pragma unroll
    for (int oi = 0; oi < 16; ++oi)
      acc[oi] = fmaf(Wct[c * 64 + ob + oi], f, acc[oi]);
  }
#pragma unroll 4
  for (int c = 0; c < 64; ++c) {                // rh
    const float f = RHF32 ? rfb[(long)c * NREAL] : bf2f(rbb[(long)c * NPAD]);
#pragma unroll
    for (int oi = 0; oi < 16; ++oi)
      acc[oi] = fmaf(Wct[(32 + c) * 64 + ob + oi], f, acc[oi]);
  }
#pragma unroll 4
  for (int c = 0; c < 32; ++c) {                // A x (Z1 x-part)
    const float f = bf2f(z1b[(long)c * NPAD]);
#pragma unroll
    for (int oi = 0; oi < 16; ++oi)
      acc[oi] = fmaf(Wct[(96 + c) * 64 + ob + oi], f, acc[oi]);
  }
#pragma unroll 4
  for (int c = 0; c < 64; ++c) {                // A rh
    const float f = bf2f(r1b[(long)c * NPAD]);
#pragma unroll
    for (int oi = 0; oi < 16; ++oi)
      acc[oi] = fmaf(Wct[(128 + c) * 64 + ob + oi], f, acc[oi]);
  }
#pragma unroll 4
  for (int c = 0; c < 32; ++c) {                // A^2 x (Z2 x-part)
    const float f = bf2f(z2b[(long)c * NPAD]);
#pragma unroll
    for (int oi = 0; oi < 16; ++oi)
      acc[oi] = fmaf(Wct[(192 + c) * 64 + ob + oi], f, acc[oi]);
  }
#pragma unroll 4
  for (int c = 0; c < 64; ++c) {                // A^2 rh
    const float f = bf2f(r2b[(long)c * NPAD]);
#pragma unroll
    for (int oi = 0; oi < 16; ++oi)
      acc[oi] = fmaf(Wct[(224 + c) * 64 + ob + oi], f, acc[oi]);
  }

#pragma unroll
  for (int oi = 0; oi < 16; ++oi) {
    const int og = ob + oi;
    float v = acc[oi] + bcv[og];
    v = fminf(fmaxf(v, -15.f), 15.f);
    const float e2 = __expf(2.f * v);
    const float cv = (e2 - 1.f) / (e2 + 1.f);
    const float u = u_f[((long)b * 64 + og) * NREAL + n];
    out[((long)b * 64 + og) * NREAL + n] = u * hb[(long)og * NREAL] + (1.f - u) * cv;
  }
}

extern "C" void kernel_launch(void* const* d_in, const int* in_sizes, int n_in,
                              void* d_out, int out_size, void* d_ws, size_t ws_size,
                              hipStream_t stream) {
  const float* x   = (const float*)d_in[0];
  const float* h   = (const float*)d_in[1];
  const float* adj = (const float*)d_in[2];
  const float* Wf  = (const float*)d_in[3];
  const float* bf_ = (const float*)d_in[4];
  const float* Wu  = (const float*)d_in[5];
  const float* bu_ = (const float*)d_in[6];
  const float* Wc  = (const float*)d_in[7];
  const float* bc_ = (const float*)d_in[8];
  float* out = (float*)d_out;

  char* p = (char*)d_ws;
  auto alloc = [&](size_t bytes) { char* r = p; p += bytes; return r; };
  u16* adjb = (u16*)alloc((size_t)NPAD * NPAD * 2);       // 33.55 MB
  u16* Zg   = (u16*)alloc((size_t)1536 * NPAD * 2);       // 12.58 MB (Rhb aliases)
  u16* Rhb  = Zg;
  u16* Z1   = (u16*)alloc((size_t)1536 * NPAD * 2);
  u16* Z2   = (u16*)alloc((size_t)1536 * NPAD * 2);
  u16* Rh1  = (u16*)alloc((size_t)1024 * NPAD * 2);       // 8.39 MB
  u16* Rh2  = (u16*)alloc((size_t)1024 * NPAD * 2);
  float* uf = (float*)alloc((size_t)16 * 64 * NREAL * 4); // 16.38 MB
  float* Wgt = (float*)alloc(288 * 128 * 4);              // 147 KB
  float* Wct = (float*)alloc(288 * 64 * 4);               // 74 KB
  const size_t RHFB = (size_t)16 * 64 * NREAL * 4;
  const size_t PC = (size_t)1536 * NPAD * 4;              // 25.17 MB / chunk
  size_t used = (size_t)(p - (char*)d_ws);
  float* rhf = nullptr;
  if (ws_size >= used + RHFB) rhf = (float*)alloc(RHFB);
  used = (size_t)(p - (char*)d_ws);
  int split = 1;
  float* P = nullptr;
  if (ws_size >= used + 4 * PC) { split = 4; P = (float*)alloc(4 * PC); }
  else if (ws_size >= used + 2 * PC) { split = 2; P = (float*)alloc(2 * PC); }

  auto gemm = [&](const u16* A, const u16* B, u16* Cb, int M) {
    const long ce = (long)M * NPAD;
    if (split == 4) {
      k_gemm_bt<true><<<dim3(32, M / 128, 4), 256, 0, stream>>>(A, B, P, 32, ce);
      k_combine<4><<<dim3(M * 4), 256, 0, stream>>>(P, ce, Cb);
    } else if (split == 2) {
      k_gemm_bt<true><<<dim3(32, M / 128, 2), 256, 0, stream>>>(A, B, P, 64, ce);
      k_combine<2><<<dim3(M * 4), 256, 0, stream>>>(P, ce, Cb);
    } else {
      k_gemm_bt<false><<<dim3(32, M / 128, 1), 256, 0, stream>>>(A, B, Cb, 128, ce);
    }
  };

  k_pack_adj<<<dim3(NPAD * (NPAD / 4) / 256), 256, 0, stream>>>(adj, adjb);
  k_pack_zg <<<dim3(1536 * (NPAD / 4) / 256), 256, 0, stream>>>(x, h, Zg);
  k_pack_w  <<<dim3(144), 256, 0, stream>>>(Wf, Wu, Wc, Wgt, Wct);
  gemm(Zg, adjb, Z1, 1536);                                   // Z1 = Zg A^T
  gemm(Z1, adjb, Z2, 1536);                                   // Z2 = Z1 A^T
  k_gates<<<dim3(32, 16), 512, 0, stream>>>(x, h, Wgt, bf_, bu_, Z1, Z2,
                                            Rhb, rhf, uf);
  gemm(Rhb, adjb, Rh1, 1024);                                 // Rh1 = rh A^T
  gemm(Rh1, adjb, Rh2, 1024);                                 // Rh2 = Rh1 A^T
  if (rhf)
    k_cand<true><<<dim3(32, 16), 512, 0, stream>>>(x, h, Wct, bc_, Z1, Z2, Rhb,
                                                   Rh1, Rh2, rhf, uf, out);
  else
    k_cand<false><<<dim3(32, 16), 512, 0, stream>>>(x, h, Wct, bc_, Z1, Z2, Rhb,
                                                    Rh1, Rh2, rhf, uf, out);
}

// Round 4
// 495.109 us; speedup vs baseline: 1.5619x; 1.1040x over previous
//
#include <hip/hip_runtime.h>
#include <cstdint>

// GCGRU cell, restructured:
//   Zg = [x;h] (1536x4000)  -> Z1 = Zg A^T, Z2 = Z1 A^T      (shared by r,u)
//   gates: r,u = sigmoid(W{f,u} . [Zg;Z1;Z2] + b)            (fp32 conv)
//   rh = r*h (1024x4000)    -> Rh1 = rh A^T, Rh2 = Rh1 A^T
//   cand: c = tanh(Wc . [x,rh, Ax,Arh, A2x,A2rh] + bc);  out = u h + (1-u) c
// Diffusion GEMMs in bf16 MFMA (fp32 accum, split-K); gate/cand convs fp32.
//
// Round-4 change: GEMM rebuilt as 256x256/BK=64/8-wave with counted-vmcnt
// double-buffer (T4: never vmcnt(0) in loop; raw s_barrier, no __syncthreads
// drain), T2 XOR swizzle (row&7)<<4 via pre-swizzled global source (rule 21),
// T5 setprio. Round-3 profile: 628 TF, MfmaUtil 26%, 6.3M bank conflicts.

#define NREAL 4000
#define NPAD  4096

typedef unsigned short u16;
typedef __attribute__((ext_vector_type(8))) short short8;
typedef __attribute__((ext_vector_type(4))) float f32x4;
typedef __attribute__((ext_vector_type(4))) unsigned short u16x4;

__device__ __forceinline__ u16 f2bf(float f) {
  unsigned u = __builtin_bit_cast(unsigned, f);
  return (u16)((u + 0x7FFFu + ((u >> 16) & 1u)) >> 16);
}
__device__ __forceinline__ float bf2f(u16 b) {
  unsigned u = ((unsigned)b) << 16;
  return __builtin_bit_cast(float, u);
}

// ---- adj f32 [4000][4000] -> bf16 [4096][4096], zero-padded ----
__global__ __launch_bounds__(256) void k_pack_adj(const float* __restrict__ adj,
                                                  u16* __restrict__ out) {
  const int idx = blockIdx.x * 256 + threadIdx.x;   // 4096*1024 total
  const int m = idx >> 10;
  const int n0 = (idx & 1023) << 2;
  u16x4 o;
  if (m < NREAL && n0 < NREAL) {   // 4000%4==0 so a float4 never straddles the edge
    const float4 v = *reinterpret_cast<const float4*>(&adj[(long)m * NREAL + n0]);
    o.x = f2bf(v.x); o.y = f2bf(v.y); o.z = f2bf(v.z); o.w = f2bf(v.w);
  } else {
    o.x = 0; o.y = 0; o.z = 0; o.w = 0;
  }
  *reinterpret_cast<u16x4*>(&out[(long)m * NPAD + n0]) = o;
}

// ---- Zg bf16 [1536][4096] = rows (b*96+c): c<32 -> x, else h ----
__global__ __launch_bounds__(256) void k_pack_zg(const float* __restrict__ x,
                                                 const float* __restrict__ h,
                                                 u16* __restrict__ zg) {
  const int idx = blockIdx.x * 256 + threadIdx.x;   // 1536*1024 total
  const int row = idx >> 10;
  const int n0 = (idx & 1023) << 2;
  const int b = row / 96, c = row % 96;
  const float* src = (c < 32) ? &x[((long)b * 32 + c) * NREAL]
                              : &h[((long)b * 64 + (c - 32)) * NREAL];
  u16x4 o;
  if (n0 < NREAL) {
    const float4 v = *reinterpret_cast<const float4*>(&src[n0]);
    o.x = f2bf(v.x); o.y = f2bf(v.y); o.z = f2bf(v.z); o.w = f2bf(v.w);
  } else {
    o.x = 0; o.y = 0; o.z = 0; o.w = 0;
  }
  *reinterpret_cast<u16x4*>(&zg[(long)row * NPAD + n0]) = o;
}

// ---- W transpose pack: Wgt[c][128] = [Wf;Wu]^T, Wct[c][64] = Wc^T ----
__global__ __launch_bounds__(256) void k_pack_w(const float* __restrict__ Wf,
                                                const float* __restrict__ Wu,
                                                const float* __restrict__ Wc,
                                                float* __restrict__ Wgt,
                                                float* __restrict__ Wct) {
  const int idx = blockIdx.x * 256 + threadIdx.x;   // 144 blocks
  if (idx < 288 * 128) {
    const int c = idx >> 7, o = idx & 127;
    Wgt[idx] = (o < 64) ? Wf[o * 288 + c] : Wu[(o - 64) * 288 + c];
  }
  if (idx < 288 * 64) {
    const int c = idx >> 6, o = idx & 63;
    Wct[idx] = Wc[o * 288 + c];
  }
}

// ---- NT bf16 GEMM, 256x256 tile, BK=64, 8 waves (2M x 4N), dbuf LDS 128KB.
// C[i][m] = sum_n A[i][n]*B[m][n]. Counted-vmcnt pipeline: stage K-tile kk+1
// while computing kk; s_waitcnt vmcnt(8) (8 loads/stage stay in flight).
// LDS swizzle: logical (row, kgrp) stored at 16B-slot (kgrp ^ (row&7)) of the
// 128B row; applied by pre-swizzling the global source (linear LDS dest) and
// XOR on ds_read addresses. F32OUT: blockIdx.z K-chunk -> fp32 partials.
template<bool F32OUT>
__global__ __launch_bounds__(512, 2) void k_gemm256(const u16* __restrict__ A,
                                                    const u16* __restrict__ B,
                                                    void* __restrict__ Cout,
                                                    int ktPerChunk, long chunkElems) {
  __shared__ __align__(16) u16 As[2][256 * 64];   // 64 KB
  __shared__ __align__(16) u16 Bs[2][256 * 64];   // 64 KB
  const int tid = threadIdx.x;
  const int lane = tid & 63;
  const int wv = tid >> 6;          // 0..7
  const int wm = wv >> 2;           // 0..1   M-half of tile
  const int wn = wv & 3;            // 0..3   N-quarter
  const int bm = blockIdx.y, bn = blockIdx.x;

  // staging: load i (i=0..3 per operand) covers LDS bytes [i*8192 + tid*16).
  // row = i*64 + tid>>3; slot j = tid&7; logical kgrp j' = j ^ (row&7).
  const int srow = tid >> 3;                     // + i*64
  const int jlog = (tid & 7) ^ (srow & 7);       // pre-swizzled source k-group
  const long kt0ofs = (long)blockIdx.z * ktPerChunk * 64;
  const u16* aS = A + (long)(bm * 256 + srow) * NPAD + kt0ofs + jlog * 8;
  const u16* bS = B + (long)(bn * 256 + srow) * NPAD + kt0ofs + jlog * 8;
  const int ldst = tid * 8;                      // u16 elems (16B/thread)

  const int fr = lane & 15;
  const int ksub2 = ((lane >> 4) << 3) << 1;     // byte offset of lane's 16B

  f32x4 acc[8][4] = {};

#define STAGE(buf, kk)                                                           \
  {                                                                              \
    const long ko = (long)(kk) * 64;                                             \
    _Pragma("unroll")                                                            \
    for (int i = 0; i < 4; ++i)                                                  \
      __builtin_amdgcn_global_load_lds(                                          \
          (const __attribute__((address_space(1))) void*)(aS + (long)i * 64 * NPAD + ko), \
          (__attribute__((address_space(3))) void*)(&As[buf][i * 4096 + ldst]), 16, 0, 0); \
    _Pragma("unroll")                                                            \
    for (int i = 0; i < 4; ++i)                                                  \
      __builtin_amdgcn_global_load_lds(                                          \
          (const __attribute__((address_space(1))) void*)(bS + (long)i * 64 * NPAD + ko), \
          (__attribute__((address_space(3))) void*)(&Bs[buf][i * 4096 + ldst]), 16, 0, 0); \
  }

  STAGE(0, 0)
  int cur = 0;
  for (int kk = 0; kk < ktPerChunk; ++kk) {
    if (kk + 1 < ktPerChunk) {
      STAGE(cur ^ 1, kk + 1)
      // cur's 8 loads (issued last iter) land; the 8 just issued stay in flight
      asm volatile("s_waitcnt vmcnt(8)\ns_barrier" ::: "memory");
    } else {
      asm volatile("s_waitcnt vmcnt(0)\ns_barrier" ::: "memory");
    }
    const char* Ab = (const char*)&As[cur][0];
    const char* Bb = (const char*)&Bs[cur][0];
#pragma unroll
    for (int ks = 0; ks < 2; ++ks) {             // two 32-k slices of the K-tile
      const int k2 = (ks << 6) + ksub2;
      short8 av[8], bv[4];
#pragma unroll
      for (int mi = 0; mi < 8; ++mi) {
        const int row = (wm << 7) + (mi << 4) + fr;
        av[mi] = *(const short8*)(Ab + row * 128 + (k2 ^ ((row & 7) << 4)));
      }
#pragma unroll
      for (int ni = 0; ni < 4; ++ni) {
        const int row = (wn << 6) + (ni << 4) + fr;
        bv[ni] = *(const short8*)(Bb + row * 128 + (k2 ^ ((row & 7) << 4)));
      }
      __builtin_amdgcn_s_setprio(1);
#pragma unroll
      for (int mi = 0; mi < 8; ++mi)
#pragma unroll
        for (int ni = 0; ni < 4; ++ni)
          acc[mi][ni] = __builtin_amdgcn_mfma_f32_16x16x32_bf16(av[mi], bv[ni],
                                                                acc[mi][ni], 0, 0, 0);
      __builtin_amdgcn_s_setprio(0);
    }
    asm volatile("s_barrier" ::: "memory");      // all waves done reading cur
    cur ^= 1;
  }
#undef STAGE

  // C/D layout (m89-verified): col = lane&15, row = (lane>>4)*4 + q
  const int rb = bm * 256 + (wm << 7) + ((lane >> 4) << 2);
  const int cb = bn * 256 + (wn << 6) + fr;
  if (F32OUT) {
    float* C = (float*)Cout + (long)blockIdx.z * chunkElems;
#pragma unroll
    for (int mi = 0; mi < 8; ++mi)
#pragma unroll
      for (int ni = 0; ni < 4; ++ni)
#pragma unroll
        for (int q = 0; q < 4; ++q)
          C[(long)(rb + (mi << 4) + q) * NPAD + cb + (ni << 4)] = acc[mi][ni][q];
  } else {
    u16* C = (u16*)Cout;
#pragma unroll
    for (int mi = 0; mi < 8; ++mi)
#pragma unroll
      for (int ni = 0; ni < 4; ++ni)
#pragma unroll
        for (int q = 0; q < 4; ++q)
          C[(long)(rb + (mi << 4) + q) * NPAD + cb + (ni << 4)] = f2bf(acc[mi][ni][q]);
  }
}

// ---- sum NC fp32 partial chunks -> bf16 ----
template<int NC>
__global__ __launch_bounds__(256) void k_combine(const float* __restrict__ P,
                                                 long chunkElems,
                                                 u16* __restrict__ out) {
  const long i4 = ((long)blockIdx.x * 256 + threadIdx.x) * 4;
  f32x4 s = *reinterpret_cast<const f32x4*>(&P[i4]);
#pragma unroll
  for (int c = 1; c < NC; ++c) {
    const f32x4 v = *reinterpret_cast<const f32x4*>(&P[(long)c * chunkElems + i4]);
    s.x += v.x; s.y += v.y; s.z += v.z; s.w += v.w;
  }
  u16x4 o;
  o.x = f2bf(s.x); o.y = f2bf(s.y); o.z = f2bf(s.z); o.w = f2bf(s.w);
  *reinterpret_cast<u16x4*>(&out[i4]) = o;
}

// ---- gates: r,u = sigmoid(Wgt^T.[z;z1;z2]+b); emit rh(bf16 [+f32]), u(f32) ----
// 8 waves: wave wq owns 16 combined outputs (0-63 r, 64-127 u); lane owns 2 n.
__global__ __launch_bounds__(512) void k_gates(
    const float* __restrict__ x, const float* __restrict__ h,
    const float* __restrict__ Wgt,
    const float* __restrict__ bfv, const float* __restrict__ buv,
    const u16* __restrict__ Z1, const u16* __restrict__ Z2,
    u16* __restrict__ rh_bf, float* __restrict__ rh_f, float* __restrict__ u_f) {
  const int lane = threadIdx.x & 63;
  const int wq = __builtin_amdgcn_readfirstlane(threadIdx.x >> 6);  // 0..7
  const int b = blockIdx.y;
  const int n0 = blockIdx.x * 128 + (lane << 1);
  if (n0 >= NREAL) return;
  const int ob = wq << 4;                       // 16 outputs, combined index
  const float* xb = x + (long)b * 32 * NREAL + n0;
  const float* hb = h + (long)b * 64 * NREAL + n0;
  const u16* z1b = Z1 + (long)b * 96 * NPAD + n0;
  const u16* z2b = Z2 + (long)b * 96 * NPAD + n0;

  float a0[16] = {}, a1[16] = {};
#pragma unroll 4
  for (int c = 0; c < 32; ++c) {                // order-0: x
    const float2 f = *reinterpret_cast<const float2*>(&xb[(long)c * NREAL]);
#pragma unroll
    for (int oi = 0; oi < 16; ++oi) {
      const float w = Wgt[c * 128 + ob + oi];
      a0[oi] = fmaf(w, f.x, a0[oi]); a1[oi] = fmaf(w, f.y, a1[oi]);
    }
  }
#pragma unroll 4
  for (int c = 0; c < 64; ++c) {                // order-0: h
    const float2 f = *reinterpret_cast<const float2*>(&hb[(long)c * NREAL]);
#pragma unroll
    for (int oi = 0; oi < 16; ++oi) {
      const float w = Wgt[(32 + c) * 128 + ob + oi];
      a0[oi] = fmaf(w, f.x, a0[oi]); a1[oi] = fmaf(w, f.y, a1[oi]);
    }
  }
#pragma unroll 4
  for (int c = 0; c < 96; ++c) {                // order-1
    const unsigned pv = *reinterpret_cast<const unsigned*>(&z1b[(long)c * NPAD]);
    const float f0 = bf2f((u16)(pv & 0xffff)), f1 = bf2f((u16)(pv >> 16));
#pragma unroll
    for (int oi = 0; oi < 16; ++oi) {
      const float w = Wgt[(96 + c) * 128 + ob + oi];
      a0[oi] = fmaf(w, f0, a0[oi]); a1[oi] = fmaf(w, f1, a1[oi]);
    }
  }
#pragma unroll 4
  for (int c = 0; c < 96; ++c) {                // order-2
    const unsigned pv = *reinterpret_cast<const unsigned*>(&z2b[(long)c * NPAD]);
    const float f0 = bf2f((u16)(pv & 0xffff)), f1 = bf2f((u16)(pv >> 16));
#pragma unroll
    for (int oi = 0; oi < 16; ++oi) {
      const float w = Wgt[(192 + c) * 128 + ob + oi];
      a0[oi] = fmaf(w, f0, a0[oi]); a1[oi] = fmaf(w, f1, a1[oi]);
    }
  }

  if (wq < 4) {                                 // r outputs -> rh
#pragma unroll
    for (int oi = 0; oi < 16; ++oi) {
      const int og = ob + oi;
      const float bb = bfv[og];
      const float r0 = 1.f / (1.f + __expf(-(a0[oi] + bb)));
      const float r1 = 1.f / (1.f + __expf(-(a1[oi] + bb)));
      const float2 hv = *reinterpret_cast<const float2*>(&hb[(long)og * NREAL]);
      const float rh0 = r0 * hv.x, rh1 = r1 * hv.y;
      if (rh_f)
        *reinterpret_cast<float2*>(&rh_f[((long)b * 64 + og) * NREAL + n0]) =
            make_float2(rh0, rh1);
      const unsigned pk = (unsigned)f2bf(rh0) | ((unsigned)f2bf(rh1) << 16);
      *reinterpret_cast<unsigned*>(&rh_bf[((long)b * 64 + og) * NPAD + n0]) = pk;
    }
  } else {                                      // u outputs
#pragma unroll
    for (int oi = 0; oi < 16; ++oi) {
      const int og = (ob - 64) + oi;
      const float bb = buv[og];
      const float u0 = 1.f / (1.f + __expf(-(a0[oi] + bb)));
      const float u1 = 1.f / (1.f + __expf(-(a1[oi] + bb)));
      *reinterpret_cast<float2*>(&u_f[((long)b * 64 + og) * NREAL + n0]) =
          make_float2(u0, u1);
    }
  }
}

// ---- candidate + output: c = tanh(Wct^T.feats+bc); out = u h + (1-u) c ----
// 8 waves: o-group = wq&3 (16 outs), n-sub = wq>>2; lane owns 1 n.
template<bool RHF32>
__global__ __launch_bounds__(512) void k_cand(
    const float* __restrict__ x, const float* __restrict__ h,
    const float* __restrict__ Wct, const float* __restrict__ bcv,
    const u16* __restrict__ Z1, const u16* __restrict__ Z2,
    const u16* __restrict__ Rhb, const u16* __restrict__ Rh1,
    const u16* __restrict__ Rh2,
    const float* __restrict__ rh_f, const float* __restrict__ u_f,
    float* __restrict__ out) {
  const int lane = threadIdx.x & 63;
  const int wq = __builtin_amdgcn_readfirstlane(threadIdx.x >> 6);  // 0..7
  const int ob = (wq & 3) << 4;                 // 16 outputs
  const int n = blockIdx.x * 128 + ((wq >> 2) << 6) + lane;
  const int b = blockIdx.y;
  if (n >= NREAL) return;
  const float* xb = x + (long)b * 32 * NREAL + n;
  const float* hb = h + (long)b * 64 * NREAL + n;
  const u16* z1b = Z1 + (long)b * 96 * NPAD + n;
  const u16* z2b = Z2 + (long)b * 96 * NPAD + n;
  const u16* r1b = Rh1 + (long)b * 64 * NPAD + n;
  const u16* r2b = Rh2 + (long)b * 64 * NPAD + n;
  const float* rfb = rh_f + (long)b * 64 * NREAL + n;
  const u16* rbb = Rhb + (long)b * 64 * NPAD + n;

  float acc[16] = {};
#pragma unroll 4
  for (int c = 0; c < 32; ++c) {                // x
    const float f = xb[(long)c * NREAL];
#pragma unroll
    for (int oi = 0; oi < 16; ++oi)
      acc[oi] = fmaf(Wct[c * 64 + ob + oi], f, acc[oi]);
  }
#pragma unroll 4
  for (int c = 0; c < 64; ++c) {                // rh
    const float f = RHF32 ? rfb[(long)c * NREAL] : bf2f(rbb[(long)c * NPAD]);
#pragma unroll
    for (int oi = 0; oi < 16; ++oi)
      acc[oi] = fmaf(Wct[(32 + c) * 64 + ob + oi], f, acc[oi]);
  }
#pragma unroll 4
  for (int c = 0; c < 32; ++c) {                // A x (Z1 x-part)
    const float f = bf2f(z1b[(long)c * NPAD]);
#pragma unroll
    for (int oi = 0; oi < 16; ++oi)
      acc[oi] = fmaf(Wct[(96 + c) * 64 + ob + oi], f, acc[oi]);
  }
#pragma unroll 4
  for (int c = 0; c < 64; ++c) {                // A rh
    const float f = bf2f(r1b[(long)c * NPAD]);
#pragma unroll
    for (int oi = 0; oi < 16; ++oi)
      acc[oi] = fmaf(Wct[(128 + c) * 64 + ob + oi], f, acc[oi]);
  }
#pragma unroll 4
  for (int c = 0; c < 32; ++c) {                // A^2 x (Z2 x-part)
    const float f = bf2f(z2b[(long)c * NPAD]);
#pragma unroll
    for (int oi = 0; oi < 16; ++oi)
      acc[oi] = fmaf(Wct[(192 + c) * 64 + ob + oi], f, acc[oi]);
  }
#pragma unroll 4
  for (int c = 0; c < 64; ++c) {                // A^2 rh
    const float f = bf2f(r2b[(long)c * NPAD]);
#pragma unroll
    for (int oi = 0; oi < 16; ++oi)
      acc[oi] = fmaf(Wct[(224 + c) * 64 + ob + oi], f, acc[oi]);
  }

#pragma unroll
  for (int oi = 0; oi < 16; ++oi) {
    const int og = ob + oi;
    float v = acc[oi] + bcv[og];
    v = fminf(fmaxf(v, -15.f), 15.f);
    const float e2 = __expf(2.f * v);
    const float cv = (e2 - 1.f) / (e2 + 1.f);
    const float u = u_f[((long)b * 64 + og) * NREAL + n];
    out[((long)b * 64 + og) * NREAL + n] = u * hb[(long)og * NREAL] + (1.f - u) * cv;
  }
}

extern "C" void kernel_launch(void* const* d_in, const int* in_sizes, int n_in,
                              void* d_out, int out_size, void* d_ws, size_t ws_size,
                              hipStream_t stream) {
  const float* x   = (const float*)d_in[0];
  const float* h   = (const float*)d_in[1];
  const float* adj = (const float*)d_in[2];
  const float* Wf  = (const float*)d_in[3];
  const float* bf_ = (const float*)d_in[4];
  const float* Wu  = (const float*)d_in[5];
  const float* bu_ = (const float*)d_in[6];
  const float* Wc  = (const float*)d_in[7];
  const float* bc_ = (const float*)d_in[8];
  float* out = (float*)d_out;

  char* p = (char*)d_ws;
  auto alloc = [&](size_t bytes) { char* r = p; p += bytes; return r; };
  u16* adjb = (u16*)alloc((size_t)NPAD * NPAD * 2);       // 33.55 MB
  u16* Zg   = (u16*)alloc((size_t)1536 * NPAD * 2);       // 12.58 MB (Rhb aliases)
  u16* Rhb  = Zg;
  u16* Z1   = (u16*)alloc((size_t)1536 * NPAD * 2);
  u16* Z2   = (u16*)alloc((size_t)1536 * NPAD * 2);
  u16* Rh1  = (u16*)alloc((size_t)1024 * NPAD * 2);       // 8.39 MB
  u16* Rh2  = (u16*)alloc((size_t)1024 * NPAD * 2);
  float* uf = (float*)alloc((size_t)16 * 64 * NREAL * 4); // 16.38 MB
  float* Wgt = (float*)alloc(288 * 128 * 4);              // 147 KB
  float* Wct = (float*)alloc(288 * 64 * 4);               // 74 KB
  const size_t RHFB = (size_t)16 * 64 * NREAL * 4;
  size_t used = (size_t)(p - (char*)d_ws);
  float* rhf = nullptr;
  if (ws_size >= used + RHFB) rhf = (float*)alloc(RHFB);
  used = (size_t)(p - (char*)d_ws);

  // split-K partial buffer: sized for the largest config in use
  const size_t PZ2 = (size_t)2 * 1536 * NPAD * 4;         // 50.33 MB
  const size_t PR4 = (size_t)4 * 1024 * NPAD * 4;         // 67.11 MB
  int sZ = 1, sR = 1;
  float* P = nullptr;
  if (ws_size >= used + PR4)      { P = (float*)alloc(PR4); sZ = 2; sR = 4; }
  else if (ws_size >= used + PZ2) { P = (float*)alloc(PZ2); sZ = 2; sR = 2; }

  auto gemm = [&](const u16* Ax, const u16* Bx, u16* Cb, int M, int sk) {
    const long ce = (long)M * NPAD;
    const int mt = M / 256;
    const int kpc = 64 / sk;       // K-tiles (of 64) per chunk
    if (sk == 4) {
      k_gemm256<true><<<dim3(16, mt, 4), 512, 0, stream>>>(Ax, Bx, P, kpc, ce);
      k_combine<4><<<dim3(M * 4), 256, 0, stream>>>(P, ce, Cb);
    } else if (sk == 2) {
      k_gemm256<true><<<dim3(16, mt, 2), 512, 0, stream>>>(Ax, Bx, P, kpc, ce);
      k_combine<2><<<dim3(M * 4), 256, 0, stream>>>(P, ce, Cb);
    } else {
      k_gemm256<false><<<dim3(16, mt, 1), 512, 0, stream>>>(Ax, Bx, Cb, 64, ce);
    }
  };

  k_pack_adj<<<dim3(NPAD * (NPAD / 4) / 256), 256, 0, stream>>>(adj, adjb);
  k_pack_zg <<<dim3(1536 * (NPAD / 4) / 256), 256, 0, stream>>>(x, h, Zg);
  k_pack_w  <<<dim3(144), 256, 0, stream>>>(Wf, Wu, Wc, Wgt, Wct);
  gemm(Zg, adjb, Z1, 1536, sZ);                               // Z1 = Zg A^T
  gemm(Z1, adjb, Z2, 1536, sZ);                               // Z2 = Z1 A^T
  k_gates<<<dim3(32, 16), 512, 0, stream>>>(x, h, Wgt, bf_, bu_, Z1, Z2,
                                            Rhb, rhf, uf);
  gemm(Rhb, adjb, Rh1, 1024, sR);                             // Rh1 = rh A^T
  gemm(Rh1, adjb, Rh2, 1024, sR);                             // Rh2 = Rh1 A^T
  if (rhf)
    k_cand<true><<<dim3(32, 16), 512, 0, stream>>>(x, h, Wct, bc_, Z1, Z2, Rhb,
                                                   Rh1, Rh2, rhf, uf, out);
  else
    k_cand<false><<<dim3(32, 16), 512, 0, stream>>>(x, h, Wct, bc_, Z1, Z2, Rhb,
                                                    Rh1, Rh2, rhf, uf, out);
}